// Round 16
// baseline (79.578 us; speedup 1.0000x reference)
//
#include <hip/hip_runtime.h>
#include <hip/hip_bf16.h>

typedef unsigned short u16;
typedef __attribute__((ext_vector_type(8))) __bf16 bf16x8;
typedef __attribute__((ext_vector_type(4))) float f32x4;

#define B_ 4
#define T_ 2048
#define C_ 1024
#define H_ 64
#define GRID 256

__device__ __forceinline__ u16 f2bf(float f) {
    union { __hip_bfloat16 h; u16 u; } cv;
    cv.h = __float2bfloat16(f);
    return cv.u;
}

__device__ __forceinline__ bf16x8 cvt8r(float4 f0, float4 f1) {
    union { u16 h[8]; bf16x8 v; } ua;
    ua.h[0] = f2bf(f0.x); ua.h[1] = f2bf(f0.y);
    ua.h[2] = f2bf(f0.z); ua.h[3] = f2bf(f0.w);
    ua.h[4] = f2bf(f1.x); ua.h[5] = f2bf(f1.y);
    ua.h[6] = f2bf(f1.z); ua.h[7] = f2bf(f1.w);
    return ua.v;
}

// async global -> LDS, 16B per lane; LDS dest = uniform base + lane*16
__device__ __forceinline__ void gll16(const void* g, void* l) {
    __builtin_amdgcn_global_load_lds(
        (const __attribute__((address_space(1))) void*)g,
        (__attribute__((address_space(3))) void*)l, 16, 0, 0);
}

// ---------------- Kernel 0: W fp32 -> bf16 + barrier reset ----------------
__global__ __launch_bounds__(256) void wcvt(
    const float* __restrict__ wq, const float* __restrict__ wk,
    const float* __restrict__ wv, u16* __restrict__ wcat,
    unsigned* __restrict__ bar)
{
    if (blockIdx.x == 0 && threadIdx.x == 0) bar[0] = 0;   // re-arm grid barrier
    int e = (blockIdx.x * 256 + threadIdx.x) * 4;
    int row = e >> 10, col = e & 1023;
    const float* src = (row < 64) ? (wq + (size_t)row * C_)
                     : (row < 128) ? (wk + (size_t)(row - 64) * C_)
                                   : (wv + (size_t)(row - 128) * C_);
    float4 f = *(const float4*)(src + col);
    u16 o[4] = { f2bf(f.x), f2bf(f.y), f2bf(f.z), f2bf(f.w) };
    *(uint2*)(wcat + e) = *(uint2*)o;
}

// ---------------- Fused: qkv GEMM -> grid barrier -> attention -> merge ---
// 256 blocks x 512 thr (8 waves). Capacity >= 2 blocks/CU (64KB LDS), so all
// 256 blocks are resident regardless of placement -> spin barrier is safe.
__global__ __launch_bounds__(512) void fused(
    const float* __restrict__ x, const u16* __restrict__ wcat,
    u16* __restrict__ q, u16* __restrict__ k, u16* __restrict__ vT,
    float* __restrict__ out, unsigned* __restrict__ bar)
{
    __shared__ __align__(16) char smem[65536];

    const int tid = threadIdx.x;
    const int ln  = tid & 63;
    const int w   = tid >> 6;        // 0..7
    const int lr  = ln & 15;
    const int g   = ln >> 4;
    const int lk  = g * 8;

    // ================= phase 1: QKV projection (R15 staged GEMM) =========
    {
        char (*lds)[32768] = (char(*)[32768])smem;
        const int m0 = blockIdx.x * 32;
        const int ms = w >> 2;                         // 16-row half
        const int nh = w & 3;                          // 48-col quarter

        f32x4 acc[3] = {};

        const int xrow = w * 4 + (ln >> 4);            // local x row 0..31
        const int xc   = (ln & 15) ^ (xrow & 7);       // pre-swizzled 16B chunk
        const int wseg0 = w * 3;
        const int wlr   = ln >> 3;
        const int wc    = (ln & 7) ^ wlr;

#define STAGE(BUF, KC)                                                         \
    do {                                                                       \
        gll16(x + (size_t)(m0 + xrow) * C_ + (KC) * 64 + xc * 4,               \
              &lds[BUF][w * 1024]);                                            \
        _Pragma("unroll")                                                      \
        for (int i_ = 0; i_ < 3; ++i_) {                                       \
            int s_ = wseg0 + i_;                                               \
            gll16(wcat + (size_t)(s_ * 8 + wlr) * C_ + (KC) * 64 + wc * 8,     \
                  &lds[BUF][8192 + s_ * 1024]);                                \
        }                                                                      \
    } while (0)

        STAGE(0, 0);
        __syncthreads();

        const int ra  = ms * 16 + lr;
        const int rsw = ra & 7;

        for (int kc = 0; kc < 16; ++kc) {
            const int buf = kc & 1;
            if (kc < 15) STAGE(buf ^ 1, kc + 1);

            const char* rb = &lds[buf][0];
            const char* wb = &lds[buf][8192];

            bf16x8 a[2];
            #pragma unroll
            for (int ks = 0; ks < 2; ++ks) {
                int c0 = ks * 8 + g * 2;
                float4 fa = *(const float4*)(rb + ra * 256 + ((c0       ^ rsw) << 4));
                float4 fb = *(const float4*)(rb + ra * 256 + (((c0 + 1) ^ rsw) << 4));
                a[ks] = cvt8r(fa, fb);
            }

            #pragma unroll
            for (int j = 0; j < 3; ++j) {
                int rr = nh * 48 + j * 16 + lr;
                #pragma unroll
                for (int ks = 0; ks < 2; ++ks) {
                    int c = (ks * 4 + g) ^ (lr & 7);
                    bf16x8 b = *(const bf16x8*)(wb + rr * 128 + c * 16);
                    acc[j] = __builtin_amdgcn_mfma_f32_16x16x32_bf16(a[ks], b, acc[j], 0, 0, 0);
                }
            }

            __syncthreads();
        }
#undef STAGE

        #pragma unroll
        for (int j = 0; j < 3; ++j) {
            int n = nh * 48 + j * 16 + lr;
            #pragma unroll
            for (int i = 0; i < 4; ++i) {
                int m = m0 + ms * 16 + g * 4 + i;
                u16 val = f2bf(acc[j][i]);
                if (n < 64) {
                    q[(size_t)m * H_ + n] = val;
                } else if (n < 128) {
                    k[(size_t)m * H_ + (n - 64)] = val;
                } else {
                    int b = m >> 11, t = m & 2047;
                    vT[((size_t)b * H_ + (n - 128)) * T_ + t] = val;
                }
            }
        }
    }

    // ================= grid barrier (device-scope) ========================
    __syncthreads();
    if (tid == 0) {
        __threadfence();                               // publish q/k/vT
        atomicAdd(bar, 1u);
        while (__hip_atomic_load(bar, __ATOMIC_RELAXED, __HIP_MEMORY_SCOPE_AGENT) < GRID)
            __builtin_amdgcn_s_sleep(2);
        __threadfence();                               // acquire others' writes
    }
    __syncthreads();

    // ================= phase 2: attention (2 tiles/block, 4 segs each) ====
    // LDS: part [2][4][16][66] f32 (33792B) | mlp [2][4][16][2] f32 (1024B)
    //      | ps [8][16*72] u16 (18432B)  -> total 53248B
    float* part = (float*)smem;
    float* mlp  = part + 2 * 4 * 16 * 66;
    u16*   ps   = (u16*)(mlp + 2 * 4 * 16 * 2);

    const int ti  = w >> 2;                            // tile within block
    const int seg = w & 3;
    const int t   = blockIdx.x * 2 + ti;
    const int b   = t & 3;
    const int qt  = t >> 2;
    const int q0  = qt * 16;
    const size_t bT = (size_t)b * T_;

    const int nch = (qt >> 2) + 1;
    const int L   = (nch + 3) >> 2;
    const int c0  = seg * L;
    const int c1  = min(nch, c0 + L);

    float* myml   = mlp  + ((ti * 4 + seg) * 16) * 2;
    float* mypart = part + ((ti * 4 + seg) * 16) * 66;
    u16*   myps   = ps + w * (16 * 72);

    if (c0 >= c1) {
        if (lr == 0)
            #pragma unroll
            for (int i = 0; i < 4; ++i) {
                myml[(g * 4 + i) * 2]     = -1e30f;
                myml[(g * 4 + i) * 2 + 1] = 0.f;
            }
    } else {
        bf16x8 aq[2];
        #pragma unroll
        for (int ks = 0; ks < 2; ++ks)
            aq[ks] = *(const bf16x8*)(q + (bT + q0 + lr) * H_ + ks * 32 + lk);

        f32x4 oacc[4] = {};
        float mrow[4], lrow[4];
        #pragma unroll
        for (int i = 0; i < 4; ++i) { mrow[i] = -1e30f; lrow[i] = 0.f; }

        for (int jc = c0; jc < c1; ++jc) {
            const int kv0 = jc << 6;

            bf16x8 bk[8];
            #pragma unroll
            for (int jf = 0; jf < 4; ++jf)
                #pragma unroll
                for (int ks = 0; ks < 2; ++ks)
                    bk[jf * 2 + ks] = *(const bf16x8*)(k + (bT + kv0 + jf * 16 + lr) * H_ + ks * 32 + lk);

            f32x4 sacc[4] = {};
            #pragma unroll
            for (int jf = 0; jf < 4; ++jf)
                #pragma unroll
                for (int ks = 0; ks < 2; ++ks)
                    sacc[jf] = __builtin_amdgcn_mfma_f32_16x16x32_bf16(aq[ks], bk[jf * 2 + ks], sacc[jf], 0, 0, 0);

            bf16x8 bv[8];
            #pragma unroll
            for (int jf = 0; jf < 4; ++jf)
                #pragma unroll
                for (int ks = 0; ks < 2; ++ks)
                    bv[jf * 2 + ks] = *(const bf16x8*)(vT + ((size_t)b * H_ + jf * 16 + lr) * T_ + kv0 + ks * 32 + lk);

            const bool full = (kv0 + 63 <= q0);
            #pragma unroll
            for (int jf = 0; jf < 4; ++jf) {
                int col = kv0 + jf * 16 + lr;
                #pragma unroll
                for (int i = 0; i < 4; ++i) {
                    int row = q0 + g * 4 + i;
                    float val = sacc[jf][i] * 0.03125f;
                    sacc[jf][i] = (full || col <= row) ? val : -1e30f;
                }
            }

            float pnew[4][4];
            #pragma unroll
            for (int i = 0; i < 4; ++i) {
                float mx = fmaxf(fmaxf(sacc[0][i], sacc[1][i]), fmaxf(sacc[2][i], sacc[3][i]));
                mx = fmaxf(mx, __shfl_xor(mx, 1));
                mx = fmaxf(mx, __shfl_xor(mx, 2));
                mx = fmaxf(mx, __shfl_xor(mx, 4));
                mx = fmaxf(mx, __shfl_xor(mx, 8));
                float mnew = fmaxf(mrow[i], mx);
                float corr = __expf(mrow[i] - mnew);
                float rs = 0.f;
                #pragma unroll
                for (int jf = 0; jf < 4; ++jf) {
                    float p = __expf(sacc[jf][i] - mnew);
                    pnew[jf][i] = p;
                    rs += p;
                }
                rs += __shfl_xor(rs, 1);
                rs += __shfl_xor(rs, 2);
                rs += __shfl_xor(rs, 4);
                rs += __shfl_xor(rs, 8);
                lrow[i] = lrow[i] * corr + rs;
                mrow[i] = mnew;
                #pragma unroll
                for (int jf = 0; jf < 4; ++jf) oacc[jf][i] *= corr;
            }

            // P -> LDS (single wave: ordering via lgkmcnt)
            #pragma unroll
            for (int jf = 0; jf < 4; ++jf)
                #pragma unroll
                for (int i = 0; i < 4; ++i)
                    myps[(g * 4 + i) * 72 + jf * 16 + lr] = f2bf(pnew[jf][i]);

            #pragma unroll
            for (int ks2 = 0; ks2 < 2; ++ks2) {
                bf16x8 ap = *(const bf16x8*)(myps + lr * 72 + ks2 * 32 + lk);
                #pragma unroll
                for (int jf = 0; jf < 4; ++jf)
                    oacc[jf] = __builtin_amdgcn_mfma_f32_16x16x32_bf16(ap, bv[jf * 2 + ks2], oacc[jf], 0, 0, 0);
            }
        }

        // fp32 partials to LDS
        #pragma unroll
        for (int jf = 0; jf < 4; ++jf)
            #pragma unroll
            for (int i = 0; i < 4; ++i)
                mypart[(g * 4 + i) * 66 + jf * 16 + lr] = oacc[jf][i];
        if (lr == 0)
            #pragma unroll
            for (int i = 0; i < 4; ++i) {
                myml[(g * 4 + i) * 2]     = mrow[i];
                myml[(g * 4 + i) * 2 + 1] = lrow[i];
            }
    }

    __syncthreads();

    // ================= phase 3: merge (in-block) ==========================
    {
        const int ti2 = tid >> 8;                      // 0..1
        const int row = (tid >> 4) & 15;
        const int p   = tid & 15;
        const int t2  = blockIdx.x * 2 + ti2;
        const int b2  = t2 & 3;
        const int qt2 = t2 >> 2;

        float m[4], l[4];
        #pragma unroll
        for (int s = 0; s < 4; ++s) {
            m[s] = mlp[((ti2 * 4 + s) * 16 + row) * 2];
            l[s] = mlp[((ti2 * 4 + s) * 16 + row) * 2 + 1];
        }
        float M = fmaxf(fmaxf(m[0], m[1]), fmaxf(m[2], m[3]));

        float a0 = 0.f, a1 = 0.f, a2 = 0.f, a3 = 0.f, Lsum = 0.f;
        #pragma unroll
        for (int s = 0; s < 4; ++s) {
            if (l[s] != 0.f) {
                float wgt = __expf(m[s] - M);
                Lsum += l[s] * wgt;
                const float* pp = part + ((ti2 * 4 + s) * 16 + row) * 66 + p * 4;
                a0 += wgt * pp[0];
                a1 += wgt * pp[1];
                a2 += wgt * pp[2];
                a3 += wgt * pp[3];
            }
        }
        float inv = 1.f / Lsum;
        float4 r; r.x = a0 * inv; r.y = a1 * inv; r.z = a2 * inv; r.w = a3 * inv;
        *(float4*)(out + ((size_t)b2 * T_ + qt2 * 16 + row) * H_ + p * 4) = r;
    }
}

extern "C" void kernel_launch(void* const* d_in, const int* in_sizes, int n_in,
                              void* d_out, int out_size, void* d_ws, size_t ws_size,
                              hipStream_t stream) {
    const float* x  = (const float*)d_in[0];
    const float* wq = (const float*)d_in[1];
    const float* wk = (const float*)d_in[2];
    const float* wv = (const float*)d_in[3];

    unsigned* bar = (unsigned*)d_ws;                 // barrier counter (256B pad)
    u16* qws  = (u16*)((char*)d_ws + 256);           // 1 MB
    u16* kws  = qws + (size_t)B_ * T_ * H_;          // 1 MB
    u16* vTws = kws + (size_t)B_ * T_ * H_;          // 1 MB
    u16* wcat = vTws + (size_t)B_ * T_ * H_;         // 384 KB

    wcvt<<<192, 256, 0, stream>>>(wq, wk, wv, wcat, bar);
    fused<<<GRID, 512, 0, stream>>>(x, wcat, qws, kws, vTws, (float*)d_out, bar);
}

// Round 17
// 40.571 us; speedup vs baseline: 1.9615x; 1.9615x over previous
//
#include <hip/hip_runtime.h>
#include <hip/hip_bf16.h>

typedef unsigned short u16;
typedef __attribute__((ext_vector_type(8))) __bf16 bf16x8;
typedef __attribute__((ext_vector_type(4))) float f32x4;

#define B_ 4
#define T_ 2048
#define C_ 1024
#define H_ 64
#define NSEG 8

__device__ __forceinline__ u16 f2bf(float f) {
    union { __hip_bfloat16 h; u16 u; } cv;
    cv.h = __float2bfloat16(f);
    return cv.u;
}

__device__ __forceinline__ float bf2f(unsigned v) {
    union { unsigned u; float f; } c; c.u = v << 16; return c.f;
}

__device__ __forceinline__ bf16x8 cvt8r(float4 f0, float4 f1) {
    union { u16 h[8]; bf16x8 v; } ua;
    ua.h[0] = f2bf(f0.x); ua.h[1] = f2bf(f0.y);
    ua.h[2] = f2bf(f0.z); ua.h[3] = f2bf(f0.w);
    ua.h[4] = f2bf(f1.x); ua.h[5] = f2bf(f1.y);
    ua.h[6] = f2bf(f1.z); ua.h[7] = f2bf(f1.w);
    return ua.v;
}

// async global -> LDS, 16B per lane; LDS dest = uniform base + lane*16
__device__ __forceinline__ void gll16(const void* g, void* l) {
    __builtin_amdgcn_global_load_lds(
        (const __attribute__((address_space(1))) void*)g,
        (__attribute__((address_space(3))) void*)l, 16, 0, 0);
}

// ---------------- Kernel 0: W fp32 -> bf16 (once) ----------------
__global__ __launch_bounds__(256) void wcvt(
    const float* __restrict__ wq, const float* __restrict__ wk,
    const float* __restrict__ wv, u16* __restrict__ wcat)
{
    int e = (blockIdx.x * 256 + threadIdx.x) * 4;
    int row = e >> 10, col = e & 1023;
    const float* src = (row < 64) ? (wq + (size_t)row * C_)
                     : (row < 128) ? (wk + (size_t)(row - 64) * C_)
                                   : (wv + (size_t)(row - 128) * C_);
    float4 f = *(const float4*)(src + col);
    u16 o[4] = { f2bf(f.x), f2bf(f.y), f2bf(f.z), f2bf(f.w) };
    *(uint2*)(wcat + e) = *(uint2*)o;
}

// ---------------- Kernel 1: QKV projection -> FRAGMENT-PACKED outputs -----
// 256 blocks x 512 thr (8 waves). Tile 32 rows x 192 cols, BK=64, staged dbuf.
// Packed layouts (16B unit = 8 bf16, unit lane ln = g*16+lr):
//   qP/kP: unit[(row16 * 2 + ks) * 64 + ln] = X[row16*16 + (ln&15)][ks*32+(ln>>4)*8 ..+8]
//   vP   : unit[(kv32 * 4 + jf) * 64 + ln] = V[h = jf*16+(ln&15)][kv32*32+(ln>>4)*8 ..+8]
// Every attn fragment load becomes one contiguous 1KB wave load.
__global__ __launch_bounds__(512) void qkv(
    const float* __restrict__ x, const u16* __restrict__ wcat,
    u16* __restrict__ qP, u16* __restrict__ kP, u16* __restrict__ vP)
{
    __shared__ __align__(16) char smem[65536];

    const int tid = threadIdx.x;
    const int ln  = tid & 63;
    const int w   = tid >> 6;                      // 0..7
    const int m0  = blockIdx.x * 32;

    const int lr = ln & 15;
    const int g  = ln >> 4;
    const int ms = w >> 2;                         // 0..1 (16-row half)
    const int nh = w & 3;                          // 0..3 (48-col quarter)

    f32x4 acc[3] = {};

    char (*lds)[32768] = (char(*)[32768])smem;
    const int xrow = w * 4 + (ln >> 4);            // local x row 0..31
    const int xc   = (ln & 15) ^ (xrow & 7);       // pre-swizzled 16B chunk
    const int wseg0 = w * 3;
    const int wlr   = ln >> 3;
    const int wc    = (ln & 7) ^ wlr;

#define STAGE(BUF, KC)                                                         \
    do {                                                                       \
        gll16(x + (size_t)(m0 + xrow) * C_ + (KC) * 64 + xc * 4,               \
              &lds[BUF][w * 1024]);                                            \
        _Pragma("unroll")                                                      \
        for (int i_ = 0; i_ < 3; ++i_) {                                       \
            int s_ = wseg0 + i_;                                               \
            gll16(wcat + (size_t)(s_ * 8 + wlr) * C_ + (KC) * 64 + wc * 8,     \
                  &lds[BUF][8192 + s_ * 1024]);                                \
        }                                                                      \
    } while (0)

    STAGE(0, 0);
    __syncthreads();

    const int ra  = ms * 16 + lr;
    const int rsw = ra & 7;

    for (int kc = 0; kc < 16; ++kc) {
        const int buf = kc & 1;
        if (kc < 15) STAGE(buf ^ 1, kc + 1);

        const char* rb = &lds[buf][0];
        const char* wb = &lds[buf][8192];

        bf16x8 a[2];
        #pragma unroll
        for (int ks = 0; ks < 2; ++ks) {
            int c0 = ks * 8 + g * 2;
            float4 fa = *(const float4*)(rb + ra * 256 + ((c0       ^ rsw) << 4));
            float4 fb = *(const float4*)(rb + ra * 256 + (((c0 + 1) ^ rsw) << 4));
            a[ks] = cvt8r(fa, fb);
        }

        #pragma unroll
        for (int j = 0; j < 3; ++j) {
            int rr = nh * 48 + j * 16 + lr;
            #pragma unroll
            for (int ks = 0; ks < 2; ++ks) {
                int c = (ks * 4 + g) ^ (lr & 7);
                bf16x8 b = *(const bf16x8*)(wb + rr * 128 + c * 16);
                acc[j] = __builtin_amdgcn_mfma_f32_16x16x32_bf16(a[ks], b, acc[j], 0, 0, 0);
            }
        }

        __syncthreads();
    }
#undef STAGE

    // ---- epilogue: acc -> LDS f32 tile [32][201] -> packed coalesced writes
    float* tile = (float*)smem;                    // 32*201*4 = 25.7 KB
    #pragma unroll
    for (int j = 0; j < 3; ++j)
        #pragma unroll
        for (int i = 0; i < 4; ++i)
            tile[(ms * 16 + g * 4 + i) * 201 + nh * 48 + j * 16 + lr] = acc[j][i];
    __syncthreads();

    for (int uu = tid; uu < 768; uu += 512) {
        const int ln2 = uu & 63;
        const int lr2 = ln2 & 15;
        const int g2  = ln2 >> 4;
        if (uu < 512) {
            // Q units 0..255, K units 256..511
            const int isK = uu >> 8;
            const int rem = uu & 255;
            const int u   = rem >> 7;              // 16-row half
            const int ks  = (rem >> 6) & 1;
            const float* src = tile + (u * 16 + lr2) * 201 + isK * 64 + ks * 32 + g2 * 8;
            float4 f0 = *(const float4*)src;
            float4 f1 = *(const float4*)(src + 4);
            bf16x8 val = cvt8r(f0, f1);
            u16* dst = (isK ? kP : qP)
                     + ((size_t)(((m0 >> 4) + u) * 2 + ks) * 64 + ln2) * 8;
            *(bf16x8*)dst = val;
        } else {
            // V units: 1 kv32 group x 4 jf x 64 ln
            const int rem = uu - 512;
            const int jf  = rem >> 6;
            union { u16 h[8]; bf16x8 v; } ua;
            #pragma unroll
            for (int e = 0; e < 8; ++e)
                ua.h[e] = f2bf(tile[(g2 * 8 + e) * 201 + 128 + jf * 16 + lr2]);
            u16* dst = vP + ((size_t)((m0 >> 5) * 4 + jf) * 64 + ln2) * 8;
            *(bf16x8*)dst = ua.v;
        }
    }
}

// ---------------- Kernel 2: causal flash attention, KV-split x8 ----------
// All fragment loads are contiguous 1KB wave loads from packed buffers.
__global__ __launch_bounds__(64) void attn_part(
    const u16* __restrict__ qP, const u16* __restrict__ kP,
    const u16* __restrict__ vP, u16* __restrict__ opart,
    float* __restrict__ ml)
{
    __shared__ u16 ps[16 * 72];

    const int lane = threadIdx.x;
    const int bid  = blockIdx.x;
    const int seg  = bid & (NSEG - 1);
    const int tix  = bid >> 3;
    const int b    = tix & 3;
    const int qt   = 127 - (tix >> 2);
    const int q0   = qt * 16;

    const int lr = lane & 15;
    const int g  = lane >> 4;
    const int lk = g * 8;

    const int nch = (qt >> 2) + 1;
    const int L   = (nch + NSEG - 1) >> 3;
    const int c0  = seg * L;
    const int c1  = min(nch, c0 + L);

    if (c0 >= c1) {
        if (lr == 0)
            #pragma unroll
            for (int i = 0; i < 4; ++i) {
                ml[(size_t)bid * 32 + (g * 4 + i) * 2]     = -1e30f;
                ml[(size_t)bid * 32 + (g * 4 + i) * 2 + 1] = 0.f;
            }
        return;
    }

    // Q fragments: packed contiguous
    bf16x8 aq[2];
    #pragma unroll
    for (int ks = 0; ks < 2; ++ks)
        aq[ks] = *(const bf16x8*)(qP + ((size_t)((b * 128 + qt) * 2 + ks) * 64 + lane) * 8);

    f32x4 oacc[4] = {};
    float mrow[4], lrow[4];
    #pragma unroll
    for (int i = 0; i < 4; ++i) { mrow[i] = -1e30f; lrow[i] = 0.f; }

    for (int jc = c0; jc < c1; ++jc) {
        const int kv0 = jc << 6;

        bf16x8 bk[8];
        #pragma unroll
        for (int jf = 0; jf < 4; ++jf)
            #pragma unroll
            for (int ks = 0; ks < 2; ++ks)
                bk[jf * 2 + ks] = *(const bf16x8*)(kP +
                    ((size_t)((b * 128 + (kv0 >> 4) + jf) * 2 + ks) * 64 + lane) * 8);

        f32x4 sacc[4] = {};
        #pragma unroll
        for (int jf = 0; jf < 4; ++jf)
            #pragma unroll
            for (int ks = 0; ks < 2; ++ks)
                sacc[jf] = __builtin_amdgcn_mfma_f32_16x16x32_bf16(aq[ks], bk[jf * 2 + ks], sacc[jf], 0, 0, 0);

        // V fragments (contiguous) issued BEFORE softmax
        bf16x8 bv[8];
        #pragma unroll
        for (int ks2 = 0; ks2 < 2; ++ks2)
            #pragma unroll
            for (int jf = 0; jf < 4; ++jf)
                bv[jf * 2 + ks2] = *(const bf16x8*)(vP +
                    ((size_t)((b * 64 + (kv0 >> 5) + ks2) * 4 + jf) * 64 + lane) * 8);

        const bool full = (kv0 + 63 <= q0);
        #pragma unroll
        for (int jf = 0; jf < 4; ++jf) {
            int col = kv0 + jf * 16 + lr;
            #pragma unroll
            for (int i = 0; i < 4; ++i) {
                int row = q0 + g * 4 + i;
                float val = sacc[jf][i] * 0.03125f;
                sacc[jf][i] = (full || col <= row) ? val : -1e30f;
            }
        }

        float pnew[4][4];
        #pragma unroll
        for (int i = 0; i < 4; ++i) {
            float mx = fmaxf(fmaxf(sacc[0][i], sacc[1][i]), fmaxf(sacc[2][i], sacc[3][i]));
            mx = fmaxf(mx, __shfl_xor(mx, 1));
            mx = fmaxf(mx, __shfl_xor(mx, 2));
            mx = fmaxf(mx, __shfl_xor(mx, 4));
            mx = fmaxf(mx, __shfl_xor(mx, 8));
            float mnew = fmaxf(mrow[i], mx);
            float corr = __expf(mrow[i] - mnew);
            float rs = 0.f;
            #pragma unroll
            for (int jf = 0; jf < 4; ++jf) {
                float p = __expf(sacc[jf][i] - mnew);
                pnew[jf][i] = p;
                rs += p;
            }
            rs += __shfl_xor(rs, 1);
            rs += __shfl_xor(rs, 2);
            rs += __shfl_xor(rs, 4);
            rs += __shfl_xor(rs, 8);
            lrow[i] = lrow[i] * corr + rs;
            mrow[i] = mnew;
            #pragma unroll
            for (int jf = 0; jf < 4; ++jf) oacc[jf][i] *= corr;
        }

        // P -> LDS (C/D -> A layout) -- single wave, ordering via lgkmcnt
        #pragma unroll
        for (int jf = 0; jf < 4; ++jf)
            #pragma unroll
            for (int i = 0; i < 4; ++i)
                ps[(g * 4 + i) * 72 + jf * 16 + lr] = f2bf(pnew[jf][i]);

        #pragma unroll
        for (int ks2 = 0; ks2 < 2; ++ks2) {
            bf16x8 ap = *(const bf16x8*)(ps + lr * 72 + ks2 * 32 + lk);
            #pragma unroll
            for (int jf = 0; jf < 4; ++jf)
                oacc[jf] = __builtin_amdgcn_mfma_f32_16x16x32_bf16(ap, bv[jf * 2 + ks2], oacc[jf], 0, 0, 0);
        }
    }

    #pragma unroll
    for (int jf = 0; jf < 4; ++jf)
        #pragma unroll
        for (int i = 0; i < 4; ++i)
            opart[(size_t)bid * 1024 + (g * 4 + i) * 64 + jf * 16 + lr] = f2bf(oacc[jf][i]);
    if (lr == 0)
        #pragma unroll
        for (int i = 0; i < 4; ++i) {
            ml[(size_t)bid * 32 + (g * 4 + i) * 2]     = mrow[i];
            ml[(size_t)bid * 32 + (g * 4 + i) * 2 + 1] = lrow[i];
        }
}

// ---------------- Kernel 3: merge segments (bf16 partials) ----------------
__global__ __launch_bounds__(256) void attn_reduce(
    const u16* __restrict__ opart, const float* __restrict__ ml,
    float* __restrict__ out)
{
    const int t   = blockIdx.x;
    const int row = threadIdx.x >> 4;
    const int p   = threadIdx.x & 15;
    const int b   = t & 3;
    const int qt  = 127 - (t >> 2);

    float m[NSEG], l[NSEG];
    #pragma unroll
    for (int s = 0; s < NSEG; ++s) {
        m[s] = ml[(size_t)(t * NSEG + s) * 32 + row * 2];
        l[s] = ml[(size_t)(t * NSEG + s) * 32 + row * 2 + 1];
    }
    float M = m[0];
    #pragma unroll
    for (int s = 1; s < NSEG; ++s) M = fmaxf(M, m[s]);

    float a0 = 0.f, a1 = 0.f, a2 = 0.f, a3 = 0.f, Lsum = 0.f;
    #pragma unroll
    for (int s = 0; s < NSEG; ++s) {
        float wgt = __expf(m[s] - M);
        Lsum += l[s] * wgt;
        uint2 o = *(const uint2*)(opart + (size_t)(t * NSEG + s) * 1024 + row * 64 + p * 4);
        a0 += wgt * bf2f(o.x & 0xffffu);
        a1 += wgt * bf2f(o.x >> 16);
        a2 += wgt * bf2f(o.y & 0xffffu);
        a3 += wgt * bf2f(o.y >> 16);
    }
    float inv = 1.f / Lsum;
    float4 r; r.x = a0 * inv; r.y = a1 * inv; r.z = a2 * inv; r.w = a3 * inv;
    *(float4*)(out + ((size_t)b * T_ + qt * 16 + row) * H_ + p * 4) = r;
}

extern "C" void kernel_launch(void* const* d_in, const int* in_sizes, int n_in,
                              void* d_out, int out_size, void* d_ws, size_t ws_size,
                              hipStream_t stream) {
    const float* x  = (const float*)d_in[0];
    const float* wq = (const float*)d_in[1];
    const float* wk = (const float*)d_in[2];
    const float* wv = (const float*)d_in[3];

    u16* qPws = (u16*)d_ws;                          // 1 MB
    u16* kPws = qPws + (size_t)B_ * T_ * H_;         // 1 MB
    u16* vPws = kPws + (size_t)B_ * T_ * H_;         // 1 MB
    u16* wcat = vPws + (size_t)B_ * T_ * H_;         // 384 KB
    u16* opart = wcat + (size_t)192 * C_;            // 8.4 MB
    float* mlbuf = (float*)(opart + (size_t)4096 * 1024);  // 512 KB

    wcvt<<<192, 256, 0, stream>>>(wq, wk, wv, wcat);
    qkv<<<256, 512, 0, stream>>>(x, wcat, qPws, kPws, vPws);
    attn_part<<<4096, 64, 0, stream>>>(qPws, kPws, vPws, opart, mlbuf);
    attn_reduce<<<512, 256, 0, stream>>>(opart, mlbuf, (float*)d_out);
}